// Round 2
// baseline (229.492 us; speedup 1.0000x reference)
//
#include <hip/hip_runtime.h>

// YOLO loss: 5-scalar reduction over N*S*S cells.
// Round 2: process 2 cells per thread so pred (120 B/cell) becomes 15 aligned
// float4 loads per pair -> fewer, wider loads, more bytes in flight per wave.

#define SS 28
#define BLOCK 256

__device__ __forceinline__ void cell_loss(
    const float* pr,        // 30 floats for this cell
    float4 tb,              // target box
    const float* tc,        // 20 target class floats
    bool m,
    float& acc_cls, float& acc_noobj, float& acc_reg, float& acc_cont)
{
    float fm = m ? 1.f : 0.f;

    // ---- class loss ----
    float cls = 0.f;
    #pragma unroll
    for (int j = 0; j < 20; ++j) {
        float d = pr[10 + j] - tc[j];
        cls += d * d;
    }
    acc_cls += fm * cls;

    // ---- no-object loss (raw; *0.5 in finalize) ----
    acc_noobj += (1.f - fm) * (pr[4] * pr[4] + pr[9] * pr[9]);

    // ---- IOU, exact reference arithmetic ----
    const float invS = 1.f / 28.f;
    float txc = tb.x * invS, tyc = tb.y * invS;
    float t0 = txc - 0.5f * tb.z, t1 = tyc - 0.5f * tb.w;
    float t2 = txc + 0.5f * tb.z, t3 = tyc + 0.5f * tb.w;
    float ta = (t2 - t0) * (t3 - t1);

    float b1xc = pr[0] * invS, b1yc = pr[1] * invS;
    float a0 = b1xc - 0.5f * pr[2], a1 = b1yc - 0.5f * pr[3];
    float a2 = b1xc + 0.5f * pr[2], a3 = b1yc + 0.5f * pr[3];
    float wx = fmaxf(fminf(a2, t2) - fmaxf(a0, t0), 0.f);
    float wy = fmaxf(fminf(a3, t3) - fmaxf(a1, t1), 0.f);
    float inter = wx * wy;
    float area1 = (a2 - a0) * (a3 - a1);
    float den = area1 + ta - inter;
    float iou1 = inter / (den > 0.f ? den : 1.f);

    float b2xc = pr[5] * invS, b2yc = pr[6] * invS;
    float c0 = b2xc - 0.5f * pr[7], c1 = b2yc - 0.5f * pr[8];
    float c2 = b2xc + 0.5f * pr[7], c3 = b2yc + 0.5f * pr[8];
    wx = fmaxf(fminf(c2, t2) - fmaxf(c0, t0), 0.f);
    wy = fmaxf(fminf(c3, t3) - fmaxf(c1, t1), 0.f);
    inter = wx * wy;
    float area2 = (c2 - c0) * (c3 - c1);
    den = area2 + ta - inter;
    float iou2 = inter / (den > 0.f ? den : 1.f);

    bool take1 = iou1 > iou2;
    float best_iou = take1 ? iou1 : iou2;
    float bbx = take1 ? pr[0] : pr[5];
    float bby = take1 ? pr[1] : pr[6];
    float bbw = take1 ? pr[2] : pr[7];
    float bbh = take1 ? pr[3] : pr[8];
    float bbc = take1 ? pr[4] : pr[9];

    float dx = bbx - tb.x, dy = bby - tb.y;
    float xy = dx * dx + dy * dy;

    float wp = m ? bbw : 1.f, hp = m ? bbh : 1.f;
    float wt = m ? tb.z : 1.f, ht = m ? tb.w : 1.f;
    float dw = sqrtf(wp) - sqrtf(wt);
    float dh = sqrtf(hp) - sqrtf(ht);
    float wh = dw * dw + dh * dh;

    acc_reg += fm * (xy + wh);

    float dc = bbc - best_iou;
    acc_cont += fm * dc * dc;
}

__global__ __launch_bounds__(BLOCK) void yolo_main(
    const float4* __restrict__ pred4,   // [pairs*15]
    const float4* __restrict__ tbox4,   // [pairs*2]
    const float4* __restrict__ tcls4,   // [pairs*10]
    const int2*   __restrict__ mask2,   // [pairs]
    float4* __restrict__ block_part,    // [gridDim.x]
    int pairs)
{
    int pair = blockIdx.x * BLOCK + threadIdx.x;

    float acc_cls = 0.f, acc_noobj = 0.f, acc_reg = 0.f, acc_cont = 0.f;

    if (pair < pairs) {
        // ---- all loads issued upfront, 16B vectors ----
        float pr[60];
        {
            const float4* p = pred4 + (size_t)pair * 15;
            #pragma unroll
            for (int i = 0; i < 15; ++i) {
                float4 v = p[i];
                pr[4*i] = v.x; pr[4*i+1] = v.y; pr[4*i+2] = v.z; pr[4*i+3] = v.w;
            }
        }
        float tc[40];
        {
            const float4* t = tcls4 + (size_t)pair * 10;
            #pragma unroll
            for (int i = 0; i < 10; ++i) {
                float4 v = t[i];
                tc[4*i] = v.x; tc[4*i+1] = v.y; tc[4*i+2] = v.z; tc[4*i+3] = v.w;
            }
        }
        float4 tb0 = tbox4[(size_t)pair * 2];
        float4 tb1 = tbox4[(size_t)pair * 2 + 1];
        int2 mm = mask2[pair];

        cell_loss(pr,      tb0, tc,      mm.x != 0, acc_cls, acc_noobj, acc_reg, acc_cont);
        cell_loss(pr + 30, tb1, tc + 20, mm.y != 0, acc_cls, acc_noobj, acc_reg, acc_cont);
    }

    // ---- wave reduction (64 lanes) ----
    float4 v = make_float4(acc_cls, acc_noobj, acc_reg, acc_cont);
    #pragma unroll
    for (int off = 32; off >= 1; off >>= 1) {
        v.x += __shfl_down(v.x, off, 64);
        v.y += __shfl_down(v.y, off, 64);
        v.z += __shfl_down(v.z, off, 64);
        v.w += __shfl_down(v.w, off, 64);
    }
    __shared__ float4 sred[BLOCK / 64];
    int lane = threadIdx.x & 63;
    int wave = threadIdx.x >> 6;
    if (lane == 0) sred[wave] = v;
    __syncthreads();
    if (threadIdx.x == 0) {
        float4 r = sred[0];
        #pragma unroll
        for (int w = 1; w < BLOCK / 64; ++w) {
            r.x += sred[w].x; r.y += sred[w].y; r.z += sred[w].z; r.w += sred[w].w;
        }
        block_part[blockIdx.x] = r;
    }
}

__global__ __launch_bounds__(BLOCK) void yolo_final(
    const float4* __restrict__ part, int nparts, float* __restrict__ out, float invN)
{
    float4 v = make_float4(0.f, 0.f, 0.f, 0.f);
    for (int i = threadIdx.x; i < nparts; i += BLOCK) {
        float4 p = part[i];
        v.x += p.x; v.y += p.y; v.z += p.z; v.w += p.w;
    }
    #pragma unroll
    for (int off = 32; off >= 1; off >>= 1) {
        v.x += __shfl_down(v.x, off, 64);
        v.y += __shfl_down(v.y, off, 64);
        v.z += __shfl_down(v.z, off, 64);
        v.w += __shfl_down(v.w, off, 64);
    }
    __shared__ float4 sred[BLOCK / 64];
    int lane = threadIdx.x & 63;
    int wave = threadIdx.x >> 6;
    if (lane == 0) sred[wave] = v;
    __syncthreads();
    if (threadIdx.x == 0) {
        float4 r = sred[0];
        #pragma unroll
        for (int w = 1; w < BLOCK / 64; ++w) {
            r.x += sred[w].x; r.y += sred[w].y; r.z += sred[w].z; r.w += sred[w].w;
        }
        float cls    = r.x;
        float no_obj = 0.5f * r.y;   // L_NOOBJ
        float reg    = 5.0f * r.z;   // L_COORD
        float cont   = r.w;
        float total  = cls + no_obj + cont + reg;
        out[0] = total  * invN;
        out[1] = reg    * invN;
        out[2] = cont   * invN;
        out[3] = no_obj * invN;
        out[4] = cls    * invN;
    }
}

extern "C" void kernel_launch(void* const* d_in, const int* in_sizes, int n_in,
                              void* d_out, int out_size, void* d_ws, size_t ws_size,
                              hipStream_t stream) {
    const float* pred = (const float*)d_in[0];
    const float* tbox = (const float*)d_in[1];
    const float* tcls = (const float*)d_in[2];
    const int*   mask = (const int*)d_in[3];
    float* out = (float*)d_out;

    int cells = in_sizes[0] / 30;                 // N*S*S (even: S*S=784)
    int n_img = cells / (SS * SS);                // N
    int pairs = cells / 2;
    int nblocks = (pairs + BLOCK - 1) / BLOCK;

    float4* part = (float4*)d_ws;                 // nblocks * 16 bytes

    yolo_main<<<nblocks, BLOCK, 0, stream>>>(
        (const float4*)pred, (const float4*)tbox, (const float4*)tcls,
        (const int2*)mask, part, pairs);
    yolo_final<<<1, BLOCK, 0, stream>>>(part, nblocks, out, 1.0f / (float)n_img);
}

// Round 3
// 206.940 us; speedup vs baseline: 1.1090x; 1.1090x over previous
//
#include <hip/hip_runtime.h>

// YOLO loss: 5-scalar reduction over N*S*S cells.
// Round 3: per-block LDS staging of pred.
//   - Block = 256 threads = 256 cells. Pred chunk = 256*120 B = 30720 B,
//     loaded as 1920 coalesced dwordx4 (each cache line requested once),
//     written linearly to LDS (ds_write_b128, conflict-free),
//     read back per-cell as 15 ds_read_b64 (stride 30 floats; 4-way
//     conflict on lanes 16 apart = x1.58, budgeted ~1.4us aggregate).
//   - tcls: direct per-thread dwordx4 (L1 absorbs the 80B-stride pattern),
//     consumed immediately so the compiler doesn't need to hold 20 floats.
//   - tbox/mask: already perfectly coalesced, direct.

#define SS 28
#define BLOCK 256
#define CPB 256                      // cells per block
#define PRED_F4_PER_BLOCK (CPB * 30 / 4)   // 1920

__global__ __launch_bounds__(BLOCK) void yolo_main(
    const float4* __restrict__ pred4,   // [cells*30/4]
    const float4* __restrict__ tbox4,   // [cells]
    const float4* __restrict__ tcls4,   // [cells*5]
    const int*    __restrict__ mask,    // [cells]
    float4* __restrict__ block_part,    // [gridDim.x]
    int cells)
{
    __shared__ float p_sh[CPB * 30];    // 30720 B, natural (unpadded) layout

    const int t = threadIdx.x;
    const int blk = blockIdx.x;

    // ---- stage pred: 1920 float4 per block, coalesced, linear LDS ----
    {
        const float4* src = pred4 + (size_t)blk * PRED_F4_PER_BLOCK;
        float4* dst = (float4*)p_sh;
        #pragma unroll
        for (int i = 0; i < 8; ++i) {
            int k = i * BLOCK + t;
            if (k < PRED_F4_PER_BLOCK)      // i==7: only half the threads
                dst[k] = src[k];
        }
    }
    __syncthreads();

    const int cell = blk * CPB + t;     // cells == gridDim.x*CPB exactly

    float acc_cls = 0.f, acc_noobj = 0.f, acc_reg = 0.f, acc_cont = 0.f;

    if (cell < cells) {
        bool m = mask[cell] != 0;                 // coalesced
        float fm = m ? 1.f : 0.f;
        float4 tb = tbox4[cell];                  // coalesced

        // ---- pred from LDS: 15x ds_read_b64 ----
        float pr[30];
        {
            const float2* p2 = (const float2*)(p_sh + t * 30);  // 8B-aligned
            #pragma unroll
            for (int i = 0; i < 15; ++i) {
                float2 v = p2[i];
                pr[2 * i] = v.x; pr[2 * i + 1] = v.y;
            }
        }

        // ---- class loss: consume tcls immediately, float4 at a time ----
        {
            const float4* t4 = tcls4 + (size_t)cell * 5;
            float cls = 0.f;
            #pragma unroll
            for (int i = 0; i < 5; ++i) {
                float4 v = t4[i];
                float d0 = pr[10 + 4 * i + 0] - v.x;
                float d1 = pr[10 + 4 * i + 1] - v.y;
                float d2 = pr[10 + 4 * i + 2] - v.z;
                float d3 = pr[10 + 4 * i + 3] - v.w;
                cls += d0 * d0 + d1 * d1 + d2 * d2 + d3 * d3;
            }
            acc_cls = fm * cls;
        }

        // ---- no-object loss (raw; *0.5 in finalize) ----
        acc_noobj = (1.f - fm) * (pr[4] * pr[4] + pr[9] * pr[9]);

        // ---- IOU, exact reference arithmetic ----
        const float invS = 1.f / 28.f;
        float txc = tb.x * invS, tyc = tb.y * invS;
        float t0 = txc - 0.5f * tb.z, t1 = tyc - 0.5f * tb.w;
        float t2 = txc + 0.5f * tb.z, t3 = tyc + 0.5f * tb.w;
        float ta = (t2 - t0) * (t3 - t1);

        float b1xc = pr[0] * invS, b1yc = pr[1] * invS;
        float a0 = b1xc - 0.5f * pr[2], a1 = b1yc - 0.5f * pr[3];
        float a2 = b1xc + 0.5f * pr[2], a3 = b1yc + 0.5f * pr[3];
        float wx = fmaxf(fminf(a2, t2) - fmaxf(a0, t0), 0.f);
        float wy = fmaxf(fminf(a3, t3) - fmaxf(a1, t1), 0.f);
        float inter = wx * wy;
        float area1 = (a2 - a0) * (a3 - a1);
        float den = area1 + ta - inter;
        float iou1 = inter / (den > 0.f ? den : 1.f);

        float b2xc = pr[5] * invS, b2yc = pr[6] * invS;
        float c0 = b2xc - 0.5f * pr[7], c1 = b2yc - 0.5f * pr[8];
        float c2 = b2xc + 0.5f * pr[7], c3 = b2yc + 0.5f * pr[8];
        wx = fmaxf(fminf(c2, t2) - fmaxf(c0, t0), 0.f);
        wy = fmaxf(fminf(c3, t3) - fmaxf(c1, t1), 0.f);
        inter = wx * wy;
        float area2 = (c2 - c0) * (c3 - c1);
        den = area2 + ta - inter;
        float iou2 = inter / (den > 0.f ? den : 1.f);

        bool take1 = iou1 > iou2;
        float best_iou = take1 ? iou1 : iou2;
        float bbx = take1 ? pr[0] : pr[5];
        float bby = take1 ? pr[1] : pr[6];
        float bbw = take1 ? pr[2] : pr[7];
        float bbh = take1 ? pr[3] : pr[8];
        float bbc = take1 ? pr[4] : pr[9];

        float dx = bbx - tb.x, dy = bby - tb.y;
        float xy = dx * dx + dy * dy;

        float wp = m ? bbw : 1.f, hp = m ? bbh : 1.f;
        float wt = m ? tb.z : 1.f, ht = m ? tb.w : 1.f;
        float dw = sqrtf(wp) - sqrtf(wt);
        float dh = sqrtf(hp) - sqrtf(ht);
        float wh = dw * dw + dh * dh;

        acc_reg = fm * (xy + wh);

        float dc = bbc - best_iou;
        acc_cont = fm * dc * dc;
    }

    // ---- wave reduction (64 lanes) ----
    float4 v = make_float4(acc_cls, acc_noobj, acc_reg, acc_cont);
    #pragma unroll
    for (int off = 32; off >= 1; off >>= 1) {
        v.x += __shfl_down(v.x, off, 64);
        v.y += __shfl_down(v.y, off, 64);
        v.z += __shfl_down(v.z, off, 64);
        v.w += __shfl_down(v.w, off, 64);
    }
    __shared__ float4 sred[BLOCK / 64];
    int lane = threadIdx.x & 63;
    int wave = threadIdx.x >> 6;
    if (lane == 0) sred[wave] = v;
    __syncthreads();
    if (threadIdx.x == 0) {
        float4 r = sred[0];
        #pragma unroll
        for (int w = 1; w < BLOCK / 64; ++w) {
            r.x += sred[w].x; r.y += sred[w].y; r.z += sred[w].z; r.w += sred[w].w;
        }
        block_part[blockIdx.x] = r;
    }
}

__global__ __launch_bounds__(BLOCK) void yolo_final(
    const float4* __restrict__ part, int nparts, float* __restrict__ out, float invN)
{
    float4 v = make_float4(0.f, 0.f, 0.f, 0.f);
    for (int i = threadIdx.x; i < nparts; i += BLOCK) {
        float4 p = part[i];
        v.x += p.x; v.y += p.y; v.z += p.z; v.w += p.w;
    }
    #pragma unroll
    for (int off = 32; off >= 1; off >>= 1) {
        v.x += __shfl_down(v.x, off, 64);
        v.y += __shfl_down(v.y, off, 64);
        v.z += __shfl_down(v.z, off, 64);
        v.w += __shfl_down(v.w, off, 64);
    }
    __shared__ float4 sred[BLOCK / 64];
    int lane = threadIdx.x & 63;
    int wave = threadIdx.x >> 6;
    if (lane == 0) sred[wave] = v;
    __syncthreads();
    if (threadIdx.x == 0) {
        float4 r = sred[0];
        #pragma unroll
        for (int w = 1; w < BLOCK / 64; ++w) {
            r.x += sred[w].x; r.y += sred[w].y; r.z += sred[w].z; r.w += sred[w].w;
        }
        float cls    = r.x;
        float no_obj = 0.5f * r.y;   // L_NOOBJ
        float reg    = 5.0f * r.z;   // L_COORD
        float cont   = r.w;
        float total  = cls + no_obj + cont + reg;
        out[0] = total  * invN;
        out[1] = reg    * invN;
        out[2] = cont   * invN;
        out[3] = no_obj * invN;
        out[4] = cls    * invN;
    }
}

extern "C" void kernel_launch(void* const* d_in, const int* in_sizes, int n_in,
                              void* d_out, int out_size, void* d_ws, size_t ws_size,
                              hipStream_t stream) {
    const float* pred = (const float*)d_in[0];
    const float* tbox = (const float*)d_in[1];
    const float* tcls = (const float*)d_in[2];
    const int*   mask = (const int*)d_in[3];
    float* out = (float*)d_out;

    int cells = in_sizes[0] / 30;                 // N*S*S = 802816
    int n_img = cells / (SS * SS);                // N
    int nblocks = (cells + CPB - 1) / CPB;        // 3136, exact

    float4* part = (float4*)d_ws;                 // nblocks * 16 bytes

    yolo_main<<<nblocks, BLOCK, 0, stream>>>(
        (const float4*)pred, (const float4*)tbox, (const float4*)tcls,
        mask, part, cells);
    yolo_final<<<1, BLOCK, 0, stream>>>(part, nblocks, out, 1.0f / (float)n_img);
}

// Round 4
// 202.273 us; speedup vs baseline: 1.1346x; 1.0231x over previous
//
#include <hip/hip_runtime.h>
#include <stdint.h>

// YOLO loss, round 4: wave-private async pred staging.
//  - Each wave grid-strides over 64-cell chunks. Pred chunk = 7680 B staged
//    into the wave's OWN LDS region via __builtin_amdgcn_global_load_lds
//    (7 x size16 + 2 x size4 = 9 VM ops, zero VGPR cost), double-buffered.
//  - No __syncthreads in the loop: only the staging wave reads its LDS.
//    Manual wave-local s_waitcnt vmcnt(9) waits the CURRENT buffer's 9 ops
//    while leaving the NEXT buffer's 9 in flight (vmcnt is FIFO).
//  - tcls/tbox/mask stay direct (coalesced / L1-absorbed); their compiler
//    waits retire older staging ops for free (FIFO).
//  - __launch_bounds__(256,2): VGPR headroom so values stay live.

#define SS 28
#define BLOCK 256
#define WPB 4                        // waves per block
#define CPW 64                       // cells per wave-chunk
#define CHUNK_FLOATS (CPW * 30)      // 1920 floats = 7680 B
#define GRID 512                     // 2 blocks/CU resident (LDS-capped)

typedef const __attribute__((address_space(1))) void* gvp;
typedef __attribute__((address_space(3))) void* lvp;

// vmcnt(n) only (expcnt=7, lgkmcnt=15 -> no wait on those)
#define WAITVM(n) __builtin_amdgcn_s_waitcnt(0x0F70 | (n))

__device__ __forceinline__ void stage_chunk(const float* __restrict__ pred,
                                            long long chunk, float* ldsbuf, int lane)
{
    const float* src = pred + chunk * CHUNK_FLOATS;
    #pragma unroll
    for (int k = 0; k < 7; ++k) {
        __builtin_amdgcn_global_load_lds((gvp)(src + k * 256 + lane * 4),
                                         (lvp)(ldsbuf + k * 256), 16, 0, 0);
    }
    #pragma unroll
    for (int j = 0; j < 2; ++j) {
        __builtin_amdgcn_global_load_lds((gvp)(src + 1792 + j * 64 + lane),
                                         (lvp)(ldsbuf + 1792 + j * 64), 4, 0, 0);
    }
}

__device__ __forceinline__ void cell_loss(
    const float* __restrict__ pr,       // 30 floats (LDS or regs)
    float4 tb, const float4* __restrict__ tc4, bool m,
    float& acc_cls, float& acc_noobj, float& acc_reg, float& acc_cont)
{
    float fm = m ? 1.f : 0.f;

    // class loss: stream 5 float4 of tcls
    float cls = 0.f;
    #pragma unroll
    for (int i = 0; i < 5; ++i) {
        float4 v = tc4[i];
        float d0 = pr[10 + 4 * i + 0] - v.x;
        float d1 = pr[10 + 4 * i + 1] - v.y;
        float d2 = pr[10 + 4 * i + 2] - v.z;
        float d3 = pr[10 + 4 * i + 3] - v.w;
        cls += d0 * d0 + d1 * d1 + d2 * d2 + d3 * d3;
    }
    acc_cls += fm * cls;

    acc_noobj += (1.f - fm) * (pr[4] * pr[4] + pr[9] * pr[9]);

    const float invS = 1.f / 28.f;
    float txc = tb.x * invS, tyc = tb.y * invS;
    float t0 = txc - 0.5f * tb.z, t1 = tyc - 0.5f * tb.w;
    float t2 = txc + 0.5f * tb.z, t3 = tyc + 0.5f * tb.w;
    float ta = (t2 - t0) * (t3 - t1);

    float b1xc = pr[0] * invS, b1yc = pr[1] * invS;
    float a0 = b1xc - 0.5f * pr[2], a1 = b1yc - 0.5f * pr[3];
    float a2 = b1xc + 0.5f * pr[2], a3 = b1yc + 0.5f * pr[3];
    float wx = fmaxf(fminf(a2, t2) - fmaxf(a0, t0), 0.f);
    float wy = fmaxf(fminf(a3, t3) - fmaxf(a1, t1), 0.f);
    float inter = wx * wy;
    float area1 = (a2 - a0) * (a3 - a1);
    float den = area1 + ta - inter;
    float iou1 = inter / (den > 0.f ? den : 1.f);

    float b2xc = pr[5] * invS, b2yc = pr[6] * invS;
    float c0 = b2xc - 0.5f * pr[7], c1 = b2yc - 0.5f * pr[8];
    float c2 = b2xc + 0.5f * pr[7], c3 = b2yc + 0.5f * pr[8];
    wx = fmaxf(fminf(c2, t2) - fmaxf(c0, t0), 0.f);
    wy = fmaxf(fminf(c3, t3) - fmaxf(c1, t1), 0.f);
    inter = wx * wy;
    float area2 = (c2 - c0) * (c3 - c1);
    den = area2 + ta - inter;
    float iou2 = inter / (den > 0.f ? den : 1.f);

    bool take1 = iou1 > iou2;
    float best_iou = take1 ? iou1 : iou2;
    float bbx = take1 ? pr[0] : pr[5];
    float bby = take1 ? pr[1] : pr[6];
    float bbw = take1 ? pr[2] : pr[7];
    float bbh = take1 ? pr[3] : pr[8];
    float bbc = take1 ? pr[4] : pr[9];

    float dx = bbx - tb.x, dy = bby - tb.y;
    float xy = dx * dx + dy * dy;

    float wp = m ? bbw : 1.f, hp = m ? bbh : 1.f;
    float wt = m ? tb.z : 1.f, ht = m ? tb.w : 1.f;
    float dw = sqrtf(wp) - sqrtf(wt);
    float dh = sqrtf(hp) - sqrtf(ht);
    float wh = dw * dw + dh * dh;

    acc_reg += fm * (xy + wh);

    float dc = bbc - best_iou;
    acc_cont += fm * dc * dc;
}

__global__ __launch_bounds__(BLOCK, 2) void yolo_main(
    const float*  __restrict__ pred,    // [cells*30]
    const float4* __restrict__ tbox4,   // [cells]
    const float4* __restrict__ tcls4,   // [cells*5]
    const int*    __restrict__ mask,    // [cells]
    float4* __restrict__ block_part,    // [GRID]
    int nchunks, int cells)
{
    __shared__ float stage[WPB][2][CHUNK_FLOATS];   // 61440 B
    __shared__ float4 sred[WPB];

    const int t    = threadIdx.x;
    const int lane = t & 63;
    const int w    = t >> 6;
    const int gw   = blockIdx.x * WPB + w;          // global wave id
    const int nw   = GRID * WPB;                    // total waves

    float acc_cls = 0.f, acc_noobj = 0.f, acc_reg = 0.f, acc_cont = 0.f;

    int c = gw;
    int buf = 0;
    if (c < nchunks) stage_chunk(pred, (long long)c, &stage[w][0][0], lane);

    while (c < nchunks) {
        int cn = c + nw;
        if (cn < nchunks) {
            stage_chunk(pred, (long long)cn, &stage[w][buf ^ 1][0], lane);
            WAITVM(9);      // current buffer done; next buffer's 9 stay in flight
        } else {
            WAITVM(0);
        }

        // pull this lane's 30 pred floats from LDS (15x ds_read_b64)
        float pr[30];
        {
            const float2* p2 = (const float2*)&stage[w][buf][lane * 30];
            #pragma unroll
            for (int i = 0; i < 15; ++i) {
                float2 v = p2[i];
                pr[2 * i] = v.x; pr[2 * i + 1] = v.y;
            }
        }

        int cell = c * CPW + lane;
        bool m = mask[cell] != 0;
        float4 tb = tbox4[cell];
        cell_loss(pr, tb, tcls4 + (size_t)cell * 5, m,
                  acc_cls, acc_noobj, acc_reg, acc_cont);

        buf ^= 1;
        c = cn;
    }

    // tail cells (cells % 64 != 0): direct loads, wave 0 of block 0 only
    int tail_base = nchunks * CPW;
    if (gw == 0 && tail_base + lane < cells) {
        int cell = tail_base + lane;
        float pr[30];
        const float2* p2 = (const float2*)(pred + (size_t)cell * 30);
        #pragma unroll
        for (int i = 0; i < 15; ++i) {
            float2 v = p2[i];
            pr[2 * i] = v.x; pr[2 * i + 1] = v.y;
        }
        bool m = mask[cell] != 0;
        float4 tb = tbox4[cell];
        cell_loss(pr, tb, tcls4 + (size_t)cell * 5, m,
                  acc_cls, acc_noobj, acc_reg, acc_cont);
    }

    // wave reduction
    float4 v = make_float4(acc_cls, acc_noobj, acc_reg, acc_cont);
    #pragma unroll
    for (int off = 32; off >= 1; off >>= 1) {
        v.x += __shfl_down(v.x, off, 64);
        v.y += __shfl_down(v.y, off, 64);
        v.z += __shfl_down(v.z, off, 64);
        v.w += __shfl_down(v.w, off, 64);
    }
    if (lane == 0) sred[w] = v;
    __syncthreads();
    if (t == 0) {
        float4 r = sred[0];
        #pragma unroll
        for (int i = 1; i < WPB; ++i) {
            r.x += sred[i].x; r.y += sred[i].y; r.z += sred[i].z; r.w += sred[i].w;
        }
        block_part[blockIdx.x] = r;
    }
}

__global__ __launch_bounds__(BLOCK) void yolo_final(
    const float4* __restrict__ part, int nparts, float* __restrict__ out, float invN)
{
    float4 v = make_float4(0.f, 0.f, 0.f, 0.f);
    for (int i = threadIdx.x; i < nparts; i += BLOCK) {
        float4 p = part[i];
        v.x += p.x; v.y += p.y; v.z += p.z; v.w += p.w;
    }
    #pragma unroll
    for (int off = 32; off >= 1; off >>= 1) {
        v.x += __shfl_down(v.x, off, 64);
        v.y += __shfl_down(v.y, off, 64);
        v.z += __shfl_down(v.z, off, 64);
        v.w += __shfl_down(v.w, off, 64);
    }
    __shared__ float4 sred[BLOCK / 64];
    int lane = threadIdx.x & 63;
    int wave = threadIdx.x >> 6;
    if (lane == 0) sred[wave] = v;
    __syncthreads();
    if (threadIdx.x == 0) {
        float4 r = sred[0];
        #pragma unroll
        for (int w = 1; w < BLOCK / 64; ++w) {
            r.x += sred[w].x; r.y += sred[w].y; r.z += sred[w].z; r.w += sred[w].w;
        }
        float cls    = r.x;
        float no_obj = 0.5f * r.y;   // L_NOOBJ
        float reg    = 5.0f * r.z;   // L_COORD
        float cont   = r.w;
        float total  = cls + no_obj + cont + reg;
        out[0] = total  * invN;
        out[1] = reg    * invN;
        out[2] = cont   * invN;
        out[3] = no_obj * invN;
        out[4] = cls    * invN;
    }
}

extern "C" void kernel_launch(void* const* d_in, const int* in_sizes, int n_in,
                              void* d_out, int out_size, void* d_ws, size_t ws_size,
                              hipStream_t stream) {
    const float* pred = (const float*)d_in[0];
    const float* tbox = (const float*)d_in[1];
    const float* tcls = (const float*)d_in[2];
    const int*   mask = (const int*)d_in[3];
    float* out = (float*)d_out;

    int cells   = in_sizes[0] / 30;        // N*S*S
    int n_img   = cells / (SS * SS);       // N
    int nchunks = cells / CPW;

    float4* part = (float4*)d_ws;          // GRID * 16 bytes

    yolo_main<<<GRID, BLOCK, 0, stream>>>(
        pred, (const float4*)tbox, (const float4*)tcls, mask, part, nchunks, cells);
    yolo_final<<<1, BLOCK, 0, stream>>>(part, GRID, out, 1.0f / (float)n_img);
}